// Round 7
// baseline (354.575 us; speedup 1.0000x reference)
//
#include <hip/hip_runtime.h>

#define HIDDEN 2048
#define NB 64
#define NT 512
#define NK 49

typedef __attribute__((ext_vector_type(4))) float f32x4;
typedef __attribute__((ext_vector_type(8))) short short8;

__device__ __forceinline__ unsigned cvtpk_bf16(float a, float b) {
    unsigned r;
    asm("v_cvt_pk_bf16_f32 %0, %1, %2" : "=v"(r) : "v"(a), "v"(b));
    return r;
}

// scalar RNE f32->bf16 (convert kernel only; not perf-critical)
__device__ __forceinline__ unsigned short f2bf(float x) {
    union { float f; unsigned u; } v; v.f = x;
    unsigned r = v.u + 0x7FFF + ((v.u >> 16) & 1);
    return (unsigned short)(r >> 16);
}

// ---------------------------------------------------------------------------
// Kernel 0 v2: convert + swizzle W{g,s,v} (fp32 [49][2048]) into MFMA
// B-fragment order, K-chunk-contiguous (unchanged, proven):
//   index tau = ((m*64 + st)*4 + c)*64 + lane   (8 bf16 = 16B per entry)
// ---------------------------------------------------------------------------
__global__ __launch_bounds__(256) void convert_w(
    const float* __restrict__ Wg, const float* __restrict__ Ws,
    const float* __restrict__ Wv, unsigned short* __restrict__ Wf)
{
    int tau = blockIdx.x * 256 + threadIdx.x;      // 0..49151
    int m   = tau >> 14;
    int rem = tau & 16383;
    int st  = rem >> 8;
    int c   = (rem >> 6) & 3;
    int l   = rem & 63;
    int col = c * 16 + (l & 15);
    int k0  = st * 32 + ((l >> 4) << 3);

    const float* W = (m == 0) ? Wg : (m == 1) ? Ws : Wv;
    unsigned short out[8];
    if (col < NK) {
        const float* p = W + (size_t)col * HIDDEN + k0;
        #pragma unroll
        for (int j = 0; j < 8; j++) out[j] = f2bf(p[j]);
    } else {
        #pragma unroll
        for (int j = 0; j < 8; j++) out[j] = 0;
    }
    unsigned short* dst = Wf + (size_t)tau * 8;
    #pragma unroll
    for (int j = 0; j < 8; j++) dst[j] = out[j];
}

// ---------------------------------------------------------------------------
// Kernel 1 v5: m97-style K-loop. B chunk (16 KB, k=128) staged via
// global_load_lds DMA double-buffered; A prefetched ~2 chunks ahead into
// named P/Q register sets via inline-asm volatile global_load_dwordx4
// (pins issue placement — compiler cannot sink/serialize). One
// __syncthreads per chunk. Math identical to R2/R4/R5 (absmax 0.0156).
// ---------------------------------------------------------------------------
#define ALOADP(Ra, Rb, gst) { \
    const float* _p = ap + (size_t)(gst) * 32; \
    asm volatile("global_load_dwordx4 %0, %1, off" : "=v"(Ra) : "v"(_p)); \
    asm volatile("global_load_dwordx4 %0, %1, off" : "=v"(Rb) : "v"(_p + 4)); }

#define BDMA(srcch, buf) { \
    const short8* _s = wfp + (size_t)(srcch) * 1024 + q * 64 + lane; \
    __builtin_amdgcn_global_load_lds((const void*)(_s), \
        (void*)&lb[buf][(q + 0) * 64], 16, 0, 0); \
    __builtin_amdgcn_global_load_lds((const void*)(_s + 64), \
        (void*)&lb[buf][(q + 1) * 64], 16, 0, 0); \
    __builtin_amdgcn_global_load_lds((const void*)(_s + 128), \
        (void*)&lb[buf][(q + 2) * 64], 16, 0, 0); \
    __builtin_amdgcn_global_load_lds((const void*)(_s + 192), \
        (void*)&lb[buf][(q + 3) * 64], 16, 0, 0); }

#define STEP(Ra, Rb, lbc, sti, rgst, dorf) { \
    union { short8 v; unsigned u[4]; } a_; \
    a_.u[0] = cvtpk_bf16(Ra[0], Ra[1]); \
    a_.u[1] = cvtpk_bf16(Ra[2], Ra[3]); \
    a_.u[2] = cvtpk_bf16(Rb[0], Rb[1]); \
    a_.u[3] = cvtpk_bf16(Rb[2], Rb[3]); \
    short8 b0 = lbc[((sti) * 4 + 0) * 64 + lane]; \
    short8 b1 = lbc[((sti) * 4 + 1) * 64 + lane]; \
    short8 b2 = lbc[((sti) * 4 + 2) * 64 + lane]; \
    short8 b3 = lbc[((sti) * 4 + 3) * 64 + lane]; \
    if (dorf) { ALOADP(Ra, Rb, rgst) } \
    acc0 = __builtin_amdgcn_mfma_f32_16x16x32_bf16(a_.v, b0, acc0, 0, 0, 0); \
    acc1 = __builtin_amdgcn_mfma_f32_16x16x32_bf16(a_.v, b1, acc1, 0, 0, 0); \
    acc2 = __builtin_amdgcn_mfma_f32_16x16x32_bf16(a_.v, b2, acc2, 0, 0, 0); \
    acc3 = __builtin_amdgcn_mfma_f32_16x16x32_bf16(a_.v, b3, acc3, 0, 0, 0); }

__global__ __launch_bounds__(256) void gemm_mfma(
    const float* __restrict__ h, const float* __restrict__ s,
    const float* __restrict__ V, const unsigned short* __restrict__ Wf,
    float* __restrict__ pg, float* __restrict__ ps, float* __restrict__ pv)
{
    int w = threadIdx.x >> 6, lane = threadIdx.x & 63;
    int blk = blockIdx.x;

    const float* A; float* C; int rowBase; const unsigned short* wfm;
    if (blk < 512)       { A = h; C = pg; rowBase = blk * 64;          wfm = Wf; }
    else if (blk < 1024) { A = s; C = ps; rowBase = (blk - 512) * 64;  wfm = Wf + (size_t)16384 * 8; }
    else                 { A = V; C = pv; rowBase = (blk - 1024) * 64; wfm = Wf + (size_t)32768 * 8; }

    const float* ap = A + (size_t)(rowBase + w * 16 + (lane & 15)) * HIDDEN + ((lane >> 4) << 3);
    const short8* wfp = (const short8*)wfm;   // short8 idx = (st*4 + c)*64 + lane

    __shared__ short8 lb[2][1024];            // 2 x 16 KB B chunk buffers
    int q = w * 4;                            // this wave's 4 DMA slices

    f32x4 acc0 = {0.f, 0.f, 0.f, 0.f};
    f32x4 acc1 = acc0, acc2 = acc0, acc3 = acc0;

    // A register sets: P = even chunk, Q = odd chunk (8 f32x4 each)
    f32x4 P0, P1, P2, P3, P4, P5, P6, P7;
    f32x4 Q0, Q1, Q2, Q3, Q4, Q5, Q6, Q7;

    // prologue: A(0) -> P, B(0) -> buf0 DMA, A(1) -> Q
    ALOADP(P0, P1, 0) ALOADP(P2, P3, 1) ALOADP(P4, P5, 2) ALOADP(P6, P7, 3)
    BDMA(0, 0)
    ALOADP(Q0, Q1, 4) ALOADP(Q2, Q3, 5) ALOADP(Q4, Q5, 6) ALOADP(Q6, Q7, 7)

    #pragma unroll 1
    for (int tt = 0; tt < 8; tt++) {
        int t0 = tt * 2, t1 = t0 + 1;

        // even chunk t0: consume lb[0]+P, DMA B(t0+1)->lb[1], refill P<-A(t0+2)
        __syncthreads();
        BDMA(t0 + 1, 1)                       // t0+1 <= 15 always
        {
            const short8* lbc = &lb[0][0];
            bool rf = (t0 + 2) < 16;
            int rg = (t0 + 2) * 4;
            STEP(P0, P1, lbc, 0, rg + 0, rf)
            STEP(P2, P3, lbc, 1, rg + 1, rf)
            STEP(P4, P5, lbc, 2, rg + 2, rf)
            STEP(P6, P7, lbc, 3, rg + 3, rf)
        }

        // odd chunk t1: consume lb[1]+Q, DMA B(t1+1)->lb[0], refill Q<-A(t1+2)
        __syncthreads();
        if (t1 + 1 < 16) { BDMA(t1 + 1, 0) }
        {
            const short8* lbc = &lb[1][0];
            bool rf = (t1 + 2) < 16;
            int rg = (t1 + 2) * 4;
            STEP(Q0, Q1, lbc, 0, rg + 0, rf)
            STEP(Q2, Q3, lbc, 1, rg + 1, rf)
            STEP(Q4, Q5, lbc, 2, rg + 2, rf)
            STEP(Q6, Q7, lbc, 3, rg + 3, rf)
        }
    }

    // C/D layout (verified m89): col = lane&15, row = (lane>>4)*4 + reg
    int colb  = lane & 15;
    int rquad = (lane >> 4) << 2;
    float* crow = C + (size_t)(rowBase + w * 16 + rquad) * NK + colb;
    #pragma unroll
    for (int r = 0; r < 4; r++) {
        crow[(size_t)r * NK + 0]  = acc0[r];
        crow[(size_t)r * NK + 16] = acc1[r];
        crow[(size_t)r * NK + 32] = acc2[r];
    }
    if (colb == 0) {
        #pragma unroll
        for (int r = 0; r < 4; r++) crow[(size_t)r * NK + 48] = acc3[r];
    }
}

// fast tanh: 1 - 2/(exp(2x)+1); safe at +-inf of exp
__device__ __forceinline__ float ftanh(float x) {
    float e = __expf(2.f * x);
    return 1.f - 2.f * __builtin_amdgcn_rcpf(e + 1.f);
}

// ---------------------------------------------------------------------------
// Kernel 2: per-(b,t) scores + softmaxes. One wave per row (b,t). (unchanged)
// ---------------------------------------------------------------------------
__global__ __launch_bounds__(256) void zab_kernel(
    const float* __restrict__ pg, const float* __restrict__ ps,
    const float* __restrict__ pv, const float* __restrict__ Wh,
    float* __restrict__ alpha, float* __restrict__ beta)
{
    int w = threadIdx.x >> 6, lane = threadIdx.x & 63;
    int row = blockIdx.x * 4 + w;        // 0..32767
    int b = row >> 9;

    const float* pgrow = pg + (size_t)row * NK;
    const float* psrow = ps + (size_t)row * NK;

    // phase A: z_ext
    float va = 0.f;
    if (lane < NK)
        va = ftanh(psrow[lane] + pgrow[lane]) * Wh[lane];
    float z_ext = va;
    #pragma unroll
    for (int off = 32; off; off >>= 1) z_ext += __shfl_xor(z_ext, off);

    // phase B: z[k]
    float z = -1e30f;
    if (lane < NK) {
        const float* pvrow = pv + ((size_t)b * NK + lane) * NK;
        float acc = 0.f;
        for (int j = 0; j < NK; j++)
            acc = fmaf(ftanh(pvrow[j] + pgrow[j]), Wh[j], acc);
        z = acc;
    }

    // softmax over k (49)
    float m = z;
    #pragma unroll
    for (int off = 32; off; off >>= 1) m = fmaxf(m, __shfl_xor(m, off));
    float p = (lane < NK) ? __expf(z - m) : 0.f;
    float ssum = p;
    #pragma unroll
    for (int off = 32; off; off >>= 1) ssum += __shfl_xor(ssum, off);
    float a = p * __builtin_amdgcn_rcpf(ssum);

    if (lane < NK)
        alpha[(size_t)row * NK + lane] = a;

    // extended softmax -> beta
    float me = fmaxf(m, z_ext);
    float se = ssum * __expf(m - me) + __expf(z_ext - me);
    float bet = __expf(z_ext - me) * __builtin_amdgcn_rcpf(se);
    if (lane == 0) beta[row] = bet;
}

// ---------------------------------------------------------------------------
// Kernel 3: c_hat = beta*sent + (1-beta)*(alpha @ V). (unchanged)
// ---------------------------------------------------------------------------
__global__ __launch_bounds__(256) void chat_kernel(
    const float* __restrict__ V, const float* __restrict__ sent,
    const float* __restrict__ alpha, const float* __restrict__ beta,
    float* __restrict__ chat)
{
    int d0 = blockIdx.x * 128;
    int t0 = blockIdx.y * 32;
    int b  = blockIdx.z;

    __shared__ float alpha_s[NK][36];   // transposed: [k][t], stride 36
    __shared__ float beta_s[32];

    int tid = threadIdx.x;

    const float* arow = alpha + ((size_t)b * NT + t0) * NK;  // 1568 contiguous
    for (int i = tid; i < 32 * NK; i += 256) {
        int t = i / NK, k = i - t * NK;
        alpha_s[k][t] = arow[i];
    }
    if (tid < 32) beta_s[tid] = beta[(size_t)b * NT + t0 + tid];
    __syncthreads();

    int tx = tid & 31;          // d-group: d = d0 + tx*4
    int ty = tid >> 5;          // t-group: t = t0 + ty*4 + i

    const float* vp = V + (size_t)b * NK * HIDDEN + d0 + tx * 4;

    float4 acc[4];
    #pragma unroll
    for (int i = 0; i < 4; i++) acc[i] = make_float4(0.f, 0.f, 0.f, 0.f);

    #pragma unroll 7
    for (int k = 0; k < NK; k++) {
        float4 vv = *(const float4*)(vp + (size_t)k * HIDDEN);
        float4 a4 = *(const float4*)&alpha_s[k][ty * 4];
        acc[0].x = fmaf(a4.x, vv.x, acc[0].x);
        acc[0].y = fmaf(a4.x, vv.y, acc[0].y);
        acc[0].z = fmaf(a4.x, vv.z, acc[0].z);
        acc[0].w = fmaf(a4.x, vv.w, acc[0].w);
        acc[1].x = fmaf(a4.y, vv.x, acc[1].x);
        acc[1].y = fmaf(a4.y, vv.y, acc[1].y);
        acc[1].z = fmaf(a4.y, vv.z, acc[1].z);
        acc[1].w = fmaf(a4.y, vv.w, acc[1].w);
        acc[2].x = fmaf(a4.z, vv.x, acc[2].x);
        acc[2].y = fmaf(a4.z, vv.y, acc[2].y);
        acc[2].z = fmaf(a4.z, vv.z, acc[2].z);
        acc[2].w = fmaf(a4.z, vv.w, acc[2].w);
        acc[3].x = fmaf(a4.w, vv.x, acc[3].x);
        acc[3].y = fmaf(a4.w, vv.y, acc[3].y);
        acc[3].z = fmaf(a4.w, vv.z, acc[3].z);
        acc[3].w = fmaf(a4.w, vv.w, acc[3].w);
    }

    #pragma unroll
    for (int i = 0; i < 4; i++) {
        int t = ty * 4 + i;
        float bt = beta_s[t];
        const float* sp = sent + ((size_t)b * NT + t0 + t) * HIDDEN + d0 + tx * 4;
        float*       op = chat + ((size_t)b * NT + t0 + t) * HIDDEN + d0 + tx * 4;
        float4 sv = *(const float4*)sp;
        float4 o;
        o.x = fmaf(bt, sv.x, (1.f - bt) * acc[i].x);
        o.y = fmaf(bt, sv.y, (1.f - bt) * acc[i].y);
        o.z = fmaf(bt, sv.z, (1.f - bt) * acc[i].z);
        o.w = fmaf(bt, sv.w, (1.f - bt) * acc[i].w);
        *(float4*)op = o;
    }
}

extern "C" void kernel_launch(void* const* d_in, const int* in_sizes, int n_in,
                              void* d_out, int out_size, void* d_ws, size_t ws_size,
                              hipStream_t stream)
{
    const float* V    = (const float*)d_in[0];
    const float* h_t  = (const float*)d_in[1];
    const float* sent = (const float*)d_in[2];
    const float* Wv   = (const float*)d_in[3];
    const float* Wg   = (const float*)d_in[4];
    const float* Ws   = (const float*)d_in[5];
    const float* Wh   = (const float*)d_in[6];

    float* out   = (float*)d_out;
    float* chat  = out;                                   // B*T*HIDDEN
    float* alpha = out + (size_t)NB * NT * HIDDEN;        // B*T*K
    float* beta  = alpha + (size_t)NB * NT * NK;          // B*T

    float* ws = (float*)d_ws;
    float* pg = ws;                                       // 32768*49
    float* ps = pg + (size_t)NB * NT * NK;                // 32768*49
    float* pv = ps + (size_t)NB * NT * NK;                // 3136*49
    unsigned short* Wf = (unsigned short*)(pv + (size_t)NB * NK * NK); // 3*16384*8 bf16

    convert_w<<<192, 256, 0, stream>>>(Wg, Ws, Wv, Wf);
    gemm_mfma<<<1073, 256, 0, stream>>>(h_t, sent, V, Wf, pg, ps, pv);
    zab_kernel<<<(NB * NT) / 4, 256, 0, stream>>>(pg, ps, pv, Wh, alpha, beta);
    chat_kernel<<<dim3(HIDDEN / 128, NT / 32, NB), 256, 0, stream>>>(V, sent, alpha, beta, chat);
}